// Round 3
// baseline (3295.864 us; speedup 1.0000x reference)
//
#include <hip/hip_runtime.h>

// 2-layer GRU, B=512 T=2048 IN=16 H=128 OUT=8.
// 32 WGs x 512 threads (8 waves, 2/SIMD). Wave w owns hidden rows [16w,16w+16).
// Transposed MFMA: A=weights (M=hidden), B=h/x (N=batch), D rows=hidden.
// Weights as f16 A-frags in registers. h crosses waves via double-buffered
// 4KB LDS B-frag layout, XOR swizzle chunk^nb (<=2-way on reads and writes).
// Custom barriers: lgkmcnt(0)-only (no vmcnt drain -> x prefetch and out
// stores span barriers). Out-projection fused into phase B on wave 7.

typedef unsigned int  uint;
typedef unsigned short ushort;
typedef _Float16 v8h __attribute__((ext_vector_type(8)));
typedef float    v4f __attribute__((ext_vector_type(4)));
typedef uint     v2u __attribute__((ext_vector_type(2)));

#define Tq   2048
#define INq  16
#define Hq   128
#define OUTq 8
#define BW   16

#define MFMA(a,b,c) __builtin_amdgcn_mfma_f32_16x16x32_f16((a),(b),(c),0,0,0)
#define BAR() do { asm volatile("s_waitcnt lgkmcnt(0)" ::: "memory"); \
                   __builtin_amdgcn_s_barrier(); \
                   asm volatile("" ::: "memory"); } while(0)

__device__ __forceinline__ float sigm(float x){
  return __builtin_amdgcn_rcpf(1.0f + __expf(-x));
}
__device__ __forceinline__ float tanh_f(float x){
  return 1.0f - 2.0f*__builtin_amdgcn_rcpf(__expf(2.0f*x) + 1.0f);
}
__device__ __forceinline__ uint packh2(float lo, float hi){
  _Float16 a=(_Float16)lo, b=(_Float16)hi;
  return (uint)__builtin_bit_cast(ushort,a) | ((uint)__builtin_bit_cast(ushort,b)<<16);
}
__device__ __forceinline__ v4f ld4(const float* p){
  return *reinterpret_cast<const v4f*>(p);
}

__global__ __launch_bounds__(512,2) void gru2_kernel(
    const float* __restrict__ x,
    const float* __restrict__ Wih0, const float* __restrict__ Whh0,
    const float* __restrict__ bih0, const float* __restrict__ bhh0,
    const float* __restrict__ Wih1, const float* __restrict__ Whh1,
    const float* __restrict__ bih1, const float* __restrict__ bhh1,
    const float* __restrict__ Wout, const float* __restrict__ bout,
    float* __restrict__ out)
{
  const int tid  = threadIdx.x;
  const int lane = tid & 63;
  const int w    = tid >> 6;      // wave 0..7: hidden slice [16w,16w+16)
  const int nb   = lane & 15;     // batch col (B/D col); also weight A-row sel
  const int bg   = lane >> 4;     // k-group; D row-group
  const int b0   = blockIdx.x * BW;
  const int hb   = 16*w + nb;     // weight row this lane loads (A-frag)

  __shared__ __align__(16) _Float16 hA0[2][2048];  // [buf][nb*128 + (c^nb)*8 + e]
  __shared__ __align__(16) _Float16 hA1[2][2048];
  for (int i=tid; i<2048; i+=512){ ((uint*)hA0)[i]=0u; ((uint*)hA1)[i]=0u; }

  // x(0) prefetch (per-lane direct load; all waves hit same lines in L1)
  const float* xrow = x + (size_t)(b0+nb)*Tq*INq;
  float4 xfa, xfb;
  if (bg < 2){
    xfa = *(const float4*)(xrow + 0*INq + bg*8);
    xfb = *(const float4*)(xrow + 0*INq + bg*8 + 4);
  }

  // ---------------- weights as f16 A-fragments ----------------
  v8h Fhh0[3][4], Fih1[3][4], Fhh1[3][4], Fx[3], Fo[4];
  #pragma unroll
  for (int g=0; g<3; ++g){
    const int r = g*Hq + hb;
    #pragma unroll
    for (int ks=0; ks<4; ++ks){
      const float* p0 = &Whh0[r*Hq + ks*32 + bg*8];
      const float* p1 = &Wih1[r*Hq + ks*32 + bg*8];
      const float* p2 = &Whh1[r*Hq + ks*32 + bg*8];
      v8h a, b, c;
      #pragma unroll
      for (int e=0;e<8;++e){ a[e]=(_Float16)p0[e]; b[e]=(_Float16)p1[e]; c[e]=(_Float16)p2[e]; }
      Fhh0[g][ks]=a; Fih1[g][ks]=b; Fhh1[g][ks]=c;
    }
    v8h vx;
    #pragma unroll
    for (int e=0;e<8;++e) vx[e]=(_Float16)0.f;
    if (bg < 2){
      const float* p = &Wih0[r*INq + bg*8];
      #pragma unroll
      for (int e=0;e<8;++e) vx[e]=(_Float16)p[e];
    }
    Fx[g]=vx;
  }
  #pragma unroll
  for (int ks=0; ks<4; ++ks){
    v8h v;
    #pragma unroll
    for (int e=0;e<8;++e) v[e]=(_Float16)0.f;
    if (nb < OUTq){
      const float* p = &Wout[nb*Hq + ks*32 + bg*8];
      #pragma unroll
      for (int e=0;e<8;++e) v[e]=(_Float16)p[e];
    }
    Fo[ks]=v;
  }

  // biases: per-j vectors (D rows = hidden 16w + bg*4 + j)
  const int hb4 = 16*w + bg*4;
  const v4f bR4  = ld4(bih0+hb4)      + ld4(bhh0+hb4);
  const v4f bZ4  = ld4(bih0+Hq+hb4)   + ld4(bhh0+Hq+hb4);
  const v4f bNX4 = ld4(bih0+2*Hq+hb4);
  const v4f bNH4 = ld4(bhh0+2*Hq+hb4);
  const v4f cR4  = ld4(bih1+hb4)      + ld4(bhh1+hb4);
  const v4f cZ4  = ld4(bih1+Hq+hb4)   + ld4(bhh1+Hq+hb4);
  const v4f cNX4 = ld4(bih1+2*Hq+hb4);
  const v4f cNH4 = ld4(bhh1+2*Hq+hb4);
  v4f bo4 = {0.f,0.f,0.f,0.f};
  if (bg < 2) bo4 = ld4(bout + bg*4);

  float h0s[4] = {0,0,0,0};           // h-state: hidden rows hb4+j, batch nb
  float h1s[4] = {0,0,0,0};

  // LDS offsets (halfword units). read chunk c=ks*4+bg; write 4 hidden @ c=2w+(bg>>1)
  int rb[4];
  #pragma unroll
  for (int ks=0; ks<4; ++ks) rb[ks] = nb*128 + (((ks*4+bg) ^ nb))*8;
  const int wof = nb*128 + (((2*w + (bg>>1)) ^ nb))*8 + (bg&1)*4;

  __syncthreads();

  for (int t=0; t<Tq; ++t){
    const int cur = t&1, prv = cur^1;

    // x(t) -> f16 B-frag
    v8h ax;
    #pragma unroll
    for (int e=0;e<8;++e) ax[e]=(_Float16)0.f;
    if (bg < 2){
      ax[0]=(_Float16)xfa.x; ax[1]=(_Float16)xfa.y; ax[2]=(_Float16)xfa.z; ax[3]=(_Float16)xfa.w;
      ax[4]=(_Float16)xfb.x; ax[5]=(_Float16)xfb.y; ax[6]=(_Float16)xfb.z; ax[7]=(_Float16)xfb.w;
    }

    // ---------------- phase A: layer-0 gates ----------------
    v4f aR=bR4, aZ=bZ4, aNX=bNX4, aNH=bNH4;
    aR  = MFMA(Fx[0], ax, aR);
    aZ  = MFMA(Fx[1], ax, aZ);
    aNX = MFMA(Fx[2], ax, aNX);
    // prefetch x(t+1): crosses both barriers (no vmcnt drain), ~1 step window
    if (bg < 2){
      const int tn = (t+1 < Tq) ? t+1 : Tq-1;
      xfa = *(const float4*)(xrow + tn*INq + bg*8);
      xfb = *(const float4*)(xrow + tn*INq + bg*8 + 4);
    }
    #pragma unroll
    for (int ks=0; ks<4; ++ks){
      v8h a = *(const v8h*)&hA0[prv][rb[ks]];
      aR  = MFMA(Fhh0[0][ks], a, aR);
      aZ  = MFMA(Fhh0[1][ks], a, aZ);
      aNH = MFMA(Fhh0[2][ks], a, aNH);
    }
    float hn0[4];
    #pragma unroll
    for (int j=0;j<4;++j){
      float r = sigm(aR[j]);
      float z = sigm(aZ[j]);
      float n = tanh_f(aNX[j] + r*aNH[j]);
      float h = n + z*(h0s[j]-n);
      h0s[j]=h; hn0[j]=h;
    }
    { v2u pk; pk[0]=packh2(hn0[0],hn0[1]); pk[1]=packh2(hn0[2],hn0[3]);
      *(v2u*)&hA0[cur][wof] = pk; }
    BAR();                                         // barrier 1 (lgkm only)

    // ---------------- phase B: layer-1 gates + fused out-proj ----------------
    v4f cR=cR4, cZ=cZ4, cNX=cNX4, cNH=cNH4;
    #pragma unroll
    for (int ks=0; ks<4; ++ks){
      v8h a0 = *(const v8h*)&hA0[cur][rb[ks]];
      v8h a1 = *(const v8h*)&hA1[prv][rb[ks]];
      cR  = MFMA(Fih1[0][ks], a0, cR);
      cZ  = MFMA(Fih1[1][ks], a0, cZ);
      cNX = MFMA(Fih1[2][ks], a0, cNX);
      cR  = MFMA(Fhh1[0][ks], a1, cR);
      cZ  = MFMA(Fhh1[1][ks], a1, cZ);
      cNH = MFMA(Fhh1[2][ks], a1, cNH);
    }
    if (w == 7){                                   // out(t-1) = Wout @ h1(t-1)
      v4f oac = {0.f,0.f,0.f,0.f};
      #pragma unroll
      for (int ks=0; ks<4; ++ks){
        v8h a1 = *(const v8h*)&hA1[prv][rb[ks]];
        oac = MFMA(Fo[ks], a1, oac);
      }
      if (t > 0 && bg < 2){
        float4 o;
        o.x=oac[0]+bo4[0]; o.y=oac[1]+bo4[1]; o.z=oac[2]+bo4[2]; o.w=oac[3]+bo4[3];
        *(float4*)&out[((size_t)(b0+nb)*Tq + (t-1))*OUTq + bg*4] = o;
      }
    }
    float hn1[4];
    #pragma unroll
    for (int j=0;j<4;++j){
      float r = sigm(cR[j]);
      float z = sigm(cZ[j]);
      float n = tanh_f(cNX[j] + r*cNH[j]);
      float h = n + z*(h1s[j]-n);
      h1s[j]=h; hn1[j]=h;
    }
    { v2u pk; pk[0]=packh2(hn1[0],hn1[1]); pk[1]=packh2(hn1[2],hn1[3]);
      *(v2u*)&hA1[cur][wof] = pk; }
    BAR();                                         // barrier 2 (lgkm only)
  }

  // epilogue: out(Tq-1) from hA1[(Tq-1)&1 == 1]
  if (w == 7){
    v4f oac = {0.f,0.f,0.f,0.f};
    #pragma unroll
    for (int ks=0; ks<4; ++ks){
      v8h a1 = *(const v8h*)&hA1[1][rb[ks]];
      oac = MFMA(Fo[ks], a1, oac);
    }
    if (bg < 2){
      float4 o;
      o.x=oac[0]+bo4[0]; o.y=oac[1]+bo4[1]; o.z=oac[2]+bo4[2]; o.w=oac[3]+bo4[3];
      *(float4*)&out[((size_t)(b0+nb)*Tq + (Tq-1))*OUTq + bg*4] = o;
    }
  }
}

extern "C" void kernel_launch(void* const* d_in, const int* in_sizes, int n_in,
                              void* d_out, int out_size, void* d_ws, size_t ws_size,
                              hipStream_t stream) {
  const float* x    = (const float*)d_in[0];
  const float* Wih0 = (const float*)d_in[1];
  const float* Whh0 = (const float*)d_in[2];
  const float* bih0 = (const float*)d_in[3];
  const float* bhh0 = (const float*)d_in[4];
  const float* Wih1 = (const float*)d_in[5];
  const float* Whh1 = (const float*)d_in[6];
  const float* bih1 = (const float*)d_in[7];
  const float* bhh1 = (const float*)d_in[8];
  const float* Wout = (const float*)d_in[9];
  const float* bo   = (const float*)d_in[10];
  gru2_kernel<<<dim3(32), dim3(512), 0, stream>>>(
      x, Wih0, Whh0, bih0, bhh0, Wih1, Whh1, bih1, bhh1, Wout, bo,
      (float*)d_out);
}